// Round 21
// baseline (172.216 us; speedup 1.0000x reference)
//
#include <hip/hip_runtime.h>

#define SEQ   2048
#define HID   1024
#define NHEAD 16
#define DH    64
#define S2    1024

typedef short bf16x8 __attribute__((ext_vector_type(8)));
typedef float f32x4  __attribute__((ext_vector_type(4)));

static __device__ __forceinline__ short f2bf(float f) {
    unsigned u = __float_as_uint(f);
    unsigned r = (u + 0x7fffu + ((u >> 16) & 1u)) >> 16;
    return (short)r;
}
static __device__ __forceinline__ float bf2f(short h) {
    return __uint_as_float(((unsigned)(unsigned short)h) << 16);
}
// pack two f32 -> two bf16 (RNE), single HW instruction
static __device__ __forceinline__ unsigned cvtpk(float lo, float hi) {
    unsigned r;
    asm("v_cvt_pk_bf16_f32 %0, %1, %2" : "=v"(r) : "v"(lo), "v"(hi));
    return r;
}
// raw v_exp_f32 (no OCML denormal fixup; FTZ is fine for softmax args <= 0)
static __device__ __forceinline__ float fexp2(float x) {
    return __builtin_amdgcn_exp2f(x);
}
// window base: 8-aligned, covers clip([a, a+63]) within [base, base+71]
static __device__ __forceinline__ int wbase(int a) {
    int b = a < 0 ? 0 : (a > 952 ? 952 : a);
    return b & ~7;
}

// scores are pre-scaled by log2(e) (folded into q and pos_q scales), so
// softmax uses exp2 throughout — mathematically exact.

// ---------------- prep: all fp32->bf16 converts + mask flags, ONE dispatch ----------------
__global__ __launch_bounds__(256) void prep_k(
    const float* __restrict__ hid_f, const float* __restrict__ win_f,
    const float* __restrict__ rel_f, const float* __restrict__ wpos_f,
    const float* __restrict__ wposq_f, const int* __restrict__ amask,
    short* __restrict__ hid_bf, short* __restrict__ win_bf,
    short* __restrict__ rel_bf, short* __restrict__ wpos_bf,
    short* __restrict__ wposq_bf, int* __restrict__ flags)
{
    __shared__ int sall[4], sany[4];
    const int b = blockIdx.x, tid = threadIdx.x;
    if (b < 4096) {
        const float* in; short* out; int idx;
        if (b < 1024)      { in = hid_f;  out = hid_bf;  idx = b * 256 + tid; }
        else if (b < 2560) { in = win_f;  out = win_bf;  idx = (b - 1024) * 256 + tid; }
        else {
            int t = b - 2560, sel = t >> 9;
            in  = sel == 0 ? rel_f  : (sel == 1 ? wpos_f  : wposq_f);
            out = sel == 0 ? rel_bf : (sel == 1 ? wpos_bf : wposq_bf);
            idx = (t & 511) * 256 + tid;
        }
        const float4 a = ((const float4*)in)[idx * 2];
        const float4 b4 = ((const float4*)in)[idx * 2 + 1];
        bf16x8 r;
        r[0] = f2bf(a.x); r[1] = f2bf(a.y); r[2] = f2bf(a.z); r[3] = f2bf(a.w);
        r[4] = f2bf(b4.x); r[5] = f2bf(b4.y); r[6] = f2bf(b4.z); r[7] = f2bf(b4.w);
        ((bf16x8*)out)[idx] = r;
    } else {
        const int mb = b - 4096;
        const int jt = mb & 31, it = mb >> 5;
        const int r = tid >> 2, cseg = (tid & 3) << 4;
        const int4* rp = (const int4*)(amask + (size_t)(it * 64 + r) * SEQ + jt * 64 + cseg);
        int allnz = 1, anynz = 0;
        #pragma unroll
        for (int e = 0; e < 4; ++e) {
            int4 v = rp[e];
            allnz &= (v.x != 0) & (v.y != 0) & (v.z != 0) & (v.w != 0);
            anynz |= (v.x != 0) | (v.y != 0) | (v.z != 0) | (v.w != 0);
        }
        unsigned long long ba = __ballot(allnz != 0);
        unsigned long long bo = __ballot(anynz != 0);
        const int w = tid >> 6;
        if ((tid & 63) == 0) { sall[w] = (ba == ~0ull); sany[w] = (bo != 0ull); }
        __syncthreads();
        if (tid == 0) {
            int all4 = sall[0] & sall[1] & sall[2] & sall[3];
            int any4 = sany[0] | sany[1] | sany[2] | sany[3];
            flags[it * 32 + jt] = all4 ? 2 : (any4 ? 1 : 0);
        }
    }
}

// ---------------- shared MFMA GEMM core: C[128x64] += A[128xK] * B[64xK]^T ----------------
static __device__ __forceinline__ void gemm_tile(
    const short* __restrict__ Ag, int lda,
    const short* __restrict__ Bg, int ldb,
    int K, short* As, short* Bs, f32x4 (&acc)[4][2])
{
    const int tid = threadIdx.x;
    const int lane = tid & 63, w = tid >> 6;
    const int g = lane >> 4, ln = lane & 15;
    const int wm = (w >> 1) * 64, wn = (w & 1) * 32;
    for (int kt = 0; kt < K; kt += 64) {
        __syncthreads();
        #pragma unroll
        for (int it = 0; it < 4; ++it) {
            int c = it * 256 + tid;
            int r = c >> 3, cb = c & 7;
            uint4 v = *(const uint4*)(Ag + (size_t)r * lda + kt + ((cb ^ (r & 7)) << 3));
            *(uint4*)(As + r * 64 + cb * 8) = v;
        }
        #pragma unroll
        for (int it = 0; it < 2; ++it) {
            int c = it * 256 + tid;
            int r = c >> 3, cb = c & 7;
            uint4 v = *(const uint4*)(Bg + (size_t)r * ldb + kt + ((cb ^ (r & 7)) << 3));
            *(uint4*)(Bs + r * 64 + cb * 8) = v;
        }
        __syncthreads();
        #pragma unroll
        for (int k0 = 0; k0 < 2; ++k0) {
            bf16x8 bfr[2];
            #pragma unroll
            for (int nf = 0; nf < 2; ++nf) {
                int rr = wn + nf * 16 + ln;
                int kc = (k0 * 4 + g) ^ (rr & 7);
                bfr[nf] = *(const bf16x8*)(Bs + rr * 64 + kc * 8);
            }
            #pragma unroll
            for (int mf = 0; mf < 4; ++mf) {
                int rr = wm + mf * 16 + ln;
                int kc = (k0 * 4 + g) ^ (rr & 7);
                bf16x8 afr = *(const bf16x8*)(As + rr * 64 + kc * 8);
                #pragma unroll
                for (int nf = 0; nf < 2; ++nf)
                    acc[mf][nf] = __builtin_amdgcn_mfma_f32_16x16x32_bf16(afr, bfr[nf], acc[mf][nf], 0, 0, 0);
            }
        }
    }
}

// ---------------- QKV projection + pos_k/pos_q in ONE dispatch (1024 blocks = 4/CU) ----------------
__global__ __launch_bounds__(256) void qkvpos_k(
    const short* __restrict__ hid, const short* __restrict__ win,
    const float* __restrict__ q_bias, const float* __restrict__ v_bias,
    const short* __restrict__ rel, const short* __restrict__ wpos, const short* __restrict__ wposq,
    const float* __restrict__ b_posq,
    short* __restrict__ qT, short* __restrict__ kT, short* __restrict__ vTt,
    short* __restrict__ posk, short* __restrict__ posq)
{
    __shared__ __align__(16) short As[128 * 64];
    __shared__ __align__(16) short Bs[64 * 64];
    const int tid = threadIdx.x, lane = tid & 63, w = tid >> 6;
    const int g = lane >> 4, ln = lane & 15;
    const int wm = (w >> 1) * 64, wn = (w & 1) * 32;
    const int x = blockIdx.x;
    // q / pos_q scales include log2(e) for exp2-softmax
    const float inv_s = 0.07216878364870323f * 1.4426950408889634f;
    f32x4 acc[4][2] = {};

    if (x < 768) {
        // ---- qkv ----
        const int bx = x % 48, by = x / 48;
        const int m0 = by * 128, n0 = bx * 64;
        gemm_tile(hid + (size_t)m0 * HID, HID, win + (size_t)n0 * HID, HID, HID, As, Bs, acc);
        #pragma unroll
        for (int nf = 0; nf < 2; ++nf) {
            const int n = n0 + wn + nf * 16 + ln;
            const int h = n / 192, c = n % 192;
            #pragma unroll
            for (int mf = 0; mf < 4; ++mf) {
                const int mb = m0 + wm + mf * 16 + 4 * g;
                if (c < 64) {
                    float qb = q_bias[h * 64 + c];
                    #pragma unroll
                    for (int reg = 0; reg < 4; ++reg)
                        qT[((size_t)h * SEQ + mb + reg) * DH + c] = f2bf((acc[mf][nf][reg] + qb) * inv_s);
                } else if (c < 128) {
                    #pragma unroll
                    for (int reg = 0; reg < 4; ++reg)
                        kT[((size_t)h * SEQ + mb + reg) * DH + (c - 64)] = f2bf(acc[mf][nf][reg]);
                } else {
                    float vb = v_bias[h * 64 + (c - 128)];
                    uint2 u;
                    u.x = cvtpk(acc[mf][nf][0] + vb, acc[mf][nf][1] + vb);
                    u.y = cvtpk(acc[mf][nf][2] + vb, acc[mf][nf][3] + vb);
                    *(uint2*)(vTt + ((size_t)h * DH + (c - 128)) * SEQ + mb) = u;
                }
            }
        }
    } else {
        // ---- pos ----
        const int t = x - 768;
        const int which = t >> 7, rest = t & 127;
        const int m0 = (rest / 16) * 128, n0 = (rest % 16) * 64;
        const short* Bg = (which ? wposq : wpos) + (size_t)n0 * HID;
        gemm_tile(rel + (size_t)m0 * HID, HID, Bg, HID, HID, As, Bs, acc);
        #pragma unroll
        for (int mf = 0; mf < 4; ++mf) {
            #pragma unroll
            for (int nf = 0; nf < 2; ++nf) {
                #pragma unroll
                for (int reg = 0; reg < 4; ++reg) {
                    int s = m0 + wm + mf * 16 + 4 * g + reg;
                    int o = n0 + wn + nf * 16 + ln;
                    int h = o >> 6, c = o & 63;
                    float v = acc[mf][nf][reg];
                    if (which) posq[((size_t)h * S2 + s) * DH + c] = f2bf((v + b_posq[o]) * inv_s);
                    else       posk[((size_t)h * S2 + s) * DH + c] = f2bf(v);
                }
            }
        }
    }
}

// ---------------- band GEMMs (c2p / p2c): 4 n-tiles per staged X tile ----------------
__global__ __launch_bounds__(256) void band_mfma_k(
    const short* __restrict__ qT, const short* __restrict__ kT,
    const short* __restrict__ posk, const short* __restrict__ posq,
    short* __restrict__ c2p, short* __restrict__ p2c)
{
    __shared__ __align__(16) short Xs[128 * 64];
    __shared__ __align__(16) short Ps[64 * 64];
    const int tid = threadIdx.x, lane = tid & 63, w = tid >> 6;
    const int g = lane >> 4, ln = lane & 15;
    const int m0 = blockIdx.y * 128, n0base = blockIdx.x * 256;
    const int head = blockIdx.z >> 1, which = blockIdx.z & 1;
    const short* Xg = (which ? kT : qT) + (size_t)head * SEQ * DH + (size_t)m0 * DH;
    const short* Pg0 = (which ? posq : posk) + (size_t)head * S2 * DH;
    short* outb = (which ? p2c : c2p) + (size_t)head * SEQ * S2;
    // stage X tile once (reused for 4 n-tiles)
    #pragma unroll
    for (int it = 0; it < 4; ++it) {
        int c = it * 256 + tid;
        int r = c >> 3, cb = c & 7;
        *(uint4*)(Xs + r * 64 + cb * 8) = *(const uint4*)(Xg + (size_t)r * DH + ((cb ^ (r & 7)) << 3));
    }
    const int wm = w * 32;
    for (int sub = 0; sub < 4; ++sub) {
        const int n0 = n0base + sub * 64;
        const short* Pg = Pg0 + (size_t)n0 * DH;
        __syncthreads();   // (1st iter: Xs ready; later: previous Ps reads done)
        #pragma unroll
        for (int it = 0; it < 2; ++it) {
            int c = it * 256 + tid;
            int r = c >> 3, cb = c & 7;
            *(uint4*)(Ps + r * 64 + cb * 8) = *(const uint4*)(Pg + (size_t)r * DH + ((cb ^ (r & 7)) << 3));
        }
        __syncthreads();
        f32x4 acc[2][4] = {};
        #pragma unroll
        for (int k0 = 0; k0 < 2; ++k0) {
            bf16x8 af[4];
            #pragma unroll
            for (int nf = 0; nf < 4; ++nf) {
                int rr = nf * 16 + ln;
                af[nf] = *(const bf16x8*)(Ps + rr * 64 + (((k0 * 4 + g) ^ (rr & 7)) << 3));
            }
            #pragma unroll
            for (int mf = 0; mf < 2; ++mf) {
                int rr = wm + mf * 16 + ln;
                bf16x8 xf = *(const bf16x8*)(Xs + rr * 64 + (((k0 * 4 + g) ^ (rr & 7)) << 3));
                #pragma unroll
                for (int nf = 0; nf < 4; ++nf)
                    acc[mf][nf] = __builtin_amdgcn_mfma_f32_16x16x32_bf16(af[nf], xf, acc[mf][nf], 0, 0, 0);
            }
        }
        // D[4g+reg] -> pos row (n-local), D[ln] -> X row (m-local)
        #pragma unroll
        for (int mf = 0; mf < 2; ++mf) {
            const int m = m0 + wm + mf * 16 + ln;
            #pragma unroll
            for (int nf = 0; nf < 4; ++nf) {
                uint2 u;
                u.x = cvtpk(acc[mf][nf][0], acc[mf][nf][1]);
                u.y = cvtpk(acc[mf][nf][2], acc[mf][nf][3]);
                *(uint2*)(outb + (size_t)m * S2 + n0 + nf * 16 + 4 * g) = u;
            }
        }
    }
}

// ---------------- MFMA flash attention: class-specialized staging (FULL vs SAT) ----------------
__global__ __launch_bounds__(256) void attn_mfma_k(
    const short* __restrict__ qT, const short* __restrict__ kT, const short* __restrict__ vTt,
    const short* __restrict__ c2p, const short* __restrict__ p2c,
    const int* __restrict__ amask, const int* __restrict__ flags,
    float* __restrict__ out)
{
    // two full staging buffers, 17408 shorts each:
    //   Ks [0,4096)  Vs [4096,8192)  Phw [8192,12800)  Chw [12800,17408)
    // SAT tiles use only Phw[0..64) (c2p column) and Phw[64..128) (p2c column).
    __shared__ __align__(16) char pool[69632];
    short* const lds = (short*)pool;
    const int tid = threadIdx.x, lane = tid & 63, w = tid >> 6;
    const int g = lane >> 4, ln = lane & 15;
    const int h = blockIdx.y, it = blockIdx.x;
    const int i0 = it * 64;
    const int iw = i0 + w * 16;
    const short* qh = qT + (size_t)h * SEQ * DH;
    const short* kh = kT + (size_t)h * SEQ * DH;
    const short* vh = vTt + (size_t)h * DH * SEQ;
    const short* ch = c2p + (size_t)h * SEQ * S2;
    const short* ph = p2c + (size_t)h * SEQ * S2;

    bf16x8 aq[2];
    aq[0] = *(const bf16x8*)(qh + (size_t)(iw + ln) * DH + 0  + g * 8);
    aq[1] = *(const bf16x8*)(qh + (size_t)(iw + ln) * DH + 32 + g * 8);

    f32x4 o4[4] = {};
    float mrow = -1.0e30f, lrow = 0.f;   // lane-local row stats (row i = iw + ln)

    const int fbase = it * 32;
    const int r0 = tid >> 3,          cb0 = tid & 7;
    const int r1 = (256 + tid) >> 3,  cb1 = tid & 7;
    const int ksw0 = (cb0 ^ (r0 & 7)) << 3, ksw1 = (cb1 ^ (r1 & 7)) << 3;
    const int wr = tid >> 2, wu = (tid & 3) * 16;

    uint4 kr0, kr1, vr0, vr1, cw0, cw1, pw0, pw1, cw2, pw2;
    unsigned short csat, psat;

    // sat tile: flag==2 and every s clamps to one end (d<=-576 low / d>=576 high)
    auto satof = [&](int jt, int fl) -> int {
        int dd = i0 - jt * 64;
        return (fl == 2) && (dd <= -576 || dd >= 576);
    };

    auto issue = [&](int jt, int sat) {
        const int j0 = jt * 64;
        kr0 = *(const uint4*)(kh + (size_t)(j0 + r0) * DH + ksw0);
        vr0 = *(const uint4*)(vh + (size_t)r0 * SEQ + j0 + ksw0);
        kr1 = *(const uint4*)(kh + (size_t)(j0 + r1) * DH + ksw1);
        vr1 = *(const uint4*)(vh + (size_t)r1 * SEQ + j0 + ksw1);
        if (!sat) {
            int bc = wbase(i0 + wr - j0 + 449);
            cw0 = *(const uint4*)(ch + (size_t)(i0 + wr) * S2 + bc + wu);
            cw1 = *(const uint4*)(ch + (size_t)(i0 + wr) * S2 + bc + wu + 8);
            int bp = wbase(i0 - j0 - wr + 512);
            pw0 = *(const uint4*)(ph + (size_t)(j0 + wr) * S2 + bp + wu);
            pw1 = *(const uint4*)(ph + (size_t)(j0 + wr) * S2 + bp + wu + 8);
            if (tid < 64) {
                int bc2 = wbase(i0 + tid - j0 + 449);
                cw2 = *(const uint4*)(ch + (size_t)(i0 + tid) * S2 + bc2 + 64);
                int bp2 = wbase(i0 - j0 - tid + 512);
                pw2 = *(const uint4*)(ph + (size_t)(j0 + tid) * S2 + bp2 + 64);
            }
        } else {
            if (tid < 64) {
                const int sb = (i0 - j0) < 0 ? 0 : 1023;
                csat = (unsigned short)ch[(size_t)(i0 + tid) * S2 + sb];
                psat = (unsigned short)ph[(size_t)(j0 + tid) * S2 + sb];
            }
        }
    };
    auto commit = [&](int bo, int sat) {
        short* Ks  = lds + bo;
        short* Vs  = lds + bo + 4096;
        short* Phw = lds + bo + 8192;
        short* Chw = lds + bo + 12800;
        *(uint4*)(Ks + r0 * 64 + cb0 * 8) = kr0;
        *(uint4*)(Vs + r0 * 64 + cb0 * 8) = vr0;
        *(uint4*)(Ks + r1 * 64 + cb1 * 8) = kr1;
        *(uint4*)(Vs + r1 * 64 + cb1 * 8) = vr1;
        if (!sat) {
            *(uint4*)(Chw + wr * 72 + wu) = cw0;
            *(uint4*)(Chw + wr * 72 + wu + 8) = cw1;
            *(uint4*)(Phw + wr * 72 + wu) = pw0;
            *(uint4*)(Phw + wr * 72 + wu + 8) = pw1;
            if (tid < 64) {
                *(uint4*)(Chw + tid * 72 + 64) = cw2;
                *(uint4*)(Phw + tid * 72 + 64) = pw2;
            }
        } else {
            if (tid < 64) {
                Phw[tid]      = (short)csat;
                Phw[64 + tid] = (short)psat;
            }
        }
    };

    // prologue: stage tile 0 into buffer 0
    int flag_cur = flags[fbase];
    int sat_cur = satof(0, flag_cur);
    issue(0, sat_cur);
    commit(0, sat_cur);
    __syncthreads();

    const int il = w * 16 + ln;     // i-local (this lane's row)
    const int i  = i0 + il;

    int bo = 0;
    for (int t = 0; t < 32; ++t) {
        const int j0 = t * 64;
        int flag_next = 0, sat_next = 0;
        if (t < 31) {
            flag_next = flags[fbase + t + 1];
            sat_next = satof(t + 1, flag_next);
            issue(t + 1, sat_next);
        }

        short* Ks  = lds + bo;
        short* Vs  = lds + bo + 4096;
        short* Phw = lds + bo + 8192;
        short* Chw = lds + bo + 12800;
        short* Psw = Chw + w * 1152;   // wave-private alias of Chw rows [16w,16w+16)

        if (flag_cur != 0) {
            // S^T = K Q^T: D col=ln -> i-local, row=4g+reg -> j-local
            f32x4 sfr[4];
            #pragma unroll
            for (int nf = 0; nf < 4; ++nf) sfr[nf] = (f32x4){0.f, 0.f, 0.f, 0.f};
            __builtin_amdgcn_s_setprio(1);
            #pragma unroll
            for (int k0 = 0; k0 < 2; ++k0) {
                #pragma unroll
                for (int nf = 0; nf < 4; ++nf) {
                    int rr = nf * 16 + ln;
                    bf16x8 ak = *(const bf16x8*)(Ks + rr * 64 + (((k0 * 4 + g) ^ (rr & 7)) << 3));
                    sfr[nf] = __builtin_amdgcn_mfma_f32_16x16x32_bf16(ak, aq[k0], sfr[nf], 0, 0, 0);
                }
            }
            __builtin_amdgcn_s_setprio(0);

            const int d = i0 - j0;
            float p[4][4];
            if (d >= -448 && d <= 384 && flag_cur == 2) {
                // FAST PATH: no clamps can engage; indices collapse to
                // per-tile bases + compile-time immediates.
                const int a = i - j0 + 449;                       // lane const
                const short* Cb = Chw + il * 72 + (a & 7) - 4 * g;
                const int cg = d + 512 - 4 * g;
                const int pbase = il + 288 * g;
                const int pb0 = pbase + (cg & 7);
                const int pb1 = pbase + ((cg - 1) & 7);
                const int pb2 = pbase + ((cg - 2) & 7);
                const int pb3 = pbase + ((cg - 3) & 7);
                #pragma unroll
                for (int nf = 0; nf < 4; ++nf) {
                    p[nf][0] = sfr[nf][0] + bf2f(Cb[63 - 16 * nf - 0]) + bf2f(Phw[pb0 + 1152 * nf + 0]);
                    p[nf][1] = sfr[nf][1] + bf2f(Cb[63 - 16 * nf - 1]) + bf2f(Phw[pb1 + 1152 * nf + 72]);
                    p[nf][2] = sfr[nf][2] + bf2f(Cb[63 - 16 * nf - 2]) + bf2f(Phw[pb2 + 1152 * nf + 144]);
                    p[nf][3] = sfr[nf][3] + bf2f(Cb[63 - 16 * nf - 3]) + bf2f(Phw[pb3 + 1152 * nf + 216]);
                }
            } else if (sat_cur) {
                // SATURATED PATH: slim column staging.
                // Phw[il] = c2p[i][s̄] (lane-const), Phw[64+jr] = p2c[j0+jr][s̄].
                const float cb = bf2f(Phw[il]);
                #pragma unroll
                for (int nf = 0; nf < 4; ++nf) {
                    uint2 pv = *(const uint2*)(Phw + 64 + 16 * nf + 4 * g);
                    p[nf][0] = sfr[nf][0] + cb + __uint_as_float(pv.x << 16);
                    p[nf][1] = sfr[nf][1] + cb + __uint_as_float(pv.x & 0xffff0000u);
                    p[nf][2] = sfr[nf][2] + cb + __uint_as_float(pv.y << 16);
                    p[nf][3] = sfr[nf][3] + cb + __uint_as_float(pv.y & 0xffff0000u);
                }
            } else {
                // GENERAL PATH: clamped windows + optional mask
                const short* Crow = Chw + il * 72 - wbase(i - j0 + 449);
                const int Cc = i0 - j0 + 512;
                #pragma unroll
                for (int nf = 0; nf < 4; ++nf) {
                    #pragma unroll
                    for (int reg = 0; reg < 4; ++reg) {
                        int jr = 16 * nf + 4 * g + reg;
                        int s = i - (j0 + jr) + 512; s = s < 0 ? 0 : (s > 1023 ? 1023 : s);
                        int wbp = Cc - jr; wbp = wbp < 0 ? 0 : (wbp > 952 ? 952 : wbp); wbp &= ~7;
                        float sc = sfr[nf][reg] + bf2f(Crow[s]) + bf2f(Phw[jr * 72 + (s - wbp)]);
                        if (flag_cur != 2)
                            sc = amask[(size_t)i * SEQ + (j0 + jr)] ? sc : -1.0e30f;
                        p[nf][reg] = sc;
                    }
                }
            }

            // online softmax (exp2 domain): row i lane-local + 2 cross-g shuffles
            float mx = p[0][0];
            #pragma unroll
            for (int nf = 0; nf < 4; ++nf)
                #pragma unroll
                for (int reg = 0; reg < 4; ++reg) mx = fmaxf(mx, p[nf][reg]);
            mx = fmaxf(mx, __shfl_xor(mx, 16, 64));
            mx = fmaxf(mx, __shfl_xor(mx, 32, 64));
            float nm = fmaxf(mrow, mx);
            float sc, rs = 0.f;
            if (flag_cur == 2) {
                sc = fexp2(mrow - nm);
                #pragma unroll
                for (int nf = 0; nf < 4; ++nf)
                    #pragma unroll
                    for (int reg = 0; reg < 4; ++reg) {
                        float e = fexp2(p[nf][reg] - nm);
                        p[nf][reg] = e; rs += e;
                    }
            } else {
                bool live = nm > -5.0e29f;
                sc = live ? fexp2(mrow - nm) : 1.f;
                #pragma unroll
                for (int nf = 0; nf < 4; ++nf)
                    #pragma unroll
                    for (int reg = 0; reg < 4; ++reg) {
                        float e = live ? fexp2(p[nf][reg] - nm) : 0.f;
                        p[nf][reg] = e; rs += e;
                    }
            }
            rs += __shfl_xor(rs, 16, 64);
            rs += __shfl_xor(rs, 32, 64);
            lrow = lrow * sc + rs;
            mrow = nm;

            // write P into wave-private aliased region: cvt_pk + 4 aligned b64 stores
            #pragma unroll
            for (int nf = 0; nf < 4; ++nf) {
                uint2 u;
                u.x = cvtpk(p[nf][0], p[nf][1]);
                u.y = cvtpk(p[nf][2], p[nf][3]);
                *(uint2*)(Psw + ln * 72 + 16 * nf + 4 * g) = u;
            }

            // rescale O^T: lane owns col i = ln -> lane-local scale
            #pragma unroll
            for (int mf = 0; mf < 4; ++mf)
                #pragma unroll
                for (int reg = 0; reg < 4; ++reg) o4[mf][reg] *= sc;

            // O^T += V^T * P^T
            __builtin_amdgcn_s_setprio(1);
            #pragma unroll
            for (int k0 = 0; k0 < 2; ++k0) {
                bf16x8 bp = *(const bf16x8*)(Psw + ln * 72 + k0 * 32 + g * 8);
                #pragma unroll
                for (int mf = 0; mf < 4; ++mf) {
                    int rr = mf * 16 + ln;
                    bf16x8 av = *(const bf16x8*)(Vs + rr * 64 + (((k0 * 4 + g) ^ (rr & 7)) << 3));
                    o4[mf] = __builtin_amdgcn_mfma_f32_16x16x32_bf16(av, bp, o4[mf], 0, 0, 0);
                }
            }
            __builtin_amdgcn_s_setprio(0);
        }

        if (t < 31) commit(bo ^ 17408, sat_next);   // writes go to the OTHER buffer
        __syncthreads();                            // single barrier per tile
        bo ^= 17408;
        flag_cur = flag_next;
        sat_cur = sat_next;
    }

    // ---- normalize (lane-local l) and store via LDS transpose, coalesced ----
    float rinv = (mrow > -5.0e29f && lrow > 0.f) ? 1.f / lrow : 0.f;
    __syncthreads();
    float* Tf = (float*)pool;   // 64 x 68 f32 = 17408 B (fits pool)
    #pragma unroll
    for (int mf = 0; mf < 4; ++mf)
        #pragma unroll
        for (int reg = 0; reg < 4; ++reg)
            Tf[(w * 16 + ln) * 68 + mf * 16 + 4 * g + reg] = o4[mf][reg] * rinv;
    __syncthreads();
    {
        const int r = tid >> 2, sgm = (tid & 3) << 4;
        float* dst = out + (size_t)(i0 + r) * HID + h * 64 + sgm;
        #pragma unroll
        for (int k = 0; k < 4; ++k)
            ((float4*)dst)[k] = *(float4*)(Tf + r * 68 + sgm + k * 4);
    }
}

extern "C" void kernel_launch(void* const* d_in, const int* in_sizes, int n_in,
                              void* d_out, int out_size, void* d_ws, size_t ws_size,
                              hipStream_t stream)
{
    const float* hidden  = (const float*)d_in[0];
    const int*   amask   = (const int*)  d_in[1];
    const float* W_in    = (const float*)d_in[2];
    const float* q_bias  = (const float*)d_in[3];
    const float* v_bias  = (const float*)d_in[4];
    const float* W_pos   = (const float*)d_in[5];
    const float* W_posq  = (const float*)d_in[6];
    const float* b_posq  = (const float*)d_in[7];
    const float* rel_emb = (const float*)d_in[8];
    float* out = (float*)d_out;

    short* ws = (short*)d_ws;
    // persistent (live into attn):
    short* qT   = ws;                    // 2,097,152
    short* kT   = ws + 2097152;          // 2,097,152
    short* vTt  = ws + 4194304;          // 2,097,152
    short* c2p  = ws + 6291456;          // 33,554,432
    short* p2c  = ws + 39845888;         // 33,554,432
    // scratch region:
    short* scr      = ws + 73400320;
    short* hid_bf   = scr;               // 2,097,152
    short* win_bf   = scr + 2097152;     // 3,145,728
    short* rel_bf   = scr + 5242880;     // 1,048,576
    short* wpos_bf  = scr + 6291456;     // 1,048,576
    short* wposq_bf = scr + 7340032;     // 1,048,576
    short* posk     = scr + 8388608;     // 1,048,576
    short* posq     = scr + 9437184;     // 1,048,576
    int*   flags    = (int*)(scr + 10485760); // 1,024 ints

    prep_k<<<5120, 256, 0, stream>>>(hidden, W_in, rel_emb, W_pos, W_posq, amask,
                                     hid_bf, win_bf, rel_bf, wpos_bf, wposq_bf, flags);
    qkvpos_k<<<1024, 256, 0, stream>>>(hid_bf, win_bf, q_bias, v_bias,
                                       rel_bf, wpos_bf, wposq_bf, b_posq,
                                       qT, kT, vTt, posk, posq);
    band_mfma_k<<<dim3(4, 16, 32), 256, 0, stream>>>(qT, kT, posk, posq, c2p, p2c);
    attn_mfma_k<<<dim3(32, 16), 256, 0, stream>>>(qT, kT, vTt, c2p, p2c, amask, flags, out);
}

// Round 22
// 164.882 us; speedup vs baseline: 1.0445x; 1.0445x over previous
//
#include <hip/hip_runtime.h>

#define SEQ   2048
#define HID   1024
#define NHEAD 16
#define DH    64
#define S2    1024

typedef short bf16x8 __attribute__((ext_vector_type(8)));
typedef float f32x4  __attribute__((ext_vector_type(4)));

static __device__ __forceinline__ short f2bf(float f) {
    unsigned u = __float_as_uint(f);
    unsigned r = (u + 0x7fffu + ((u >> 16) & 1u)) >> 16;
    return (short)r;
}
static __device__ __forceinline__ float bf2f(short h) {
    return __uint_as_float(((unsigned)(unsigned short)h) << 16);
}
// pack two f32 -> two bf16 (RNE), single HW instruction
static __device__ __forceinline__ unsigned cvtpk(float lo, float hi) {
    unsigned r;
    asm("v_cvt_pk_bf16_f32 %0, %1, %2" : "=v"(r) : "v"(lo), "v"(hi));
    return r;
}
// raw v_exp_f32 (no OCML denormal fixup; FTZ is fine for softmax args <= 0)
static __device__ __forceinline__ float fexp2(float x) {
    return __builtin_amdgcn_exp2f(x);
}
// window base: 8-aligned, covers clip([a, a+63]) within [base, base+71]
static __device__ __forceinline__ int wbase(int a) {
    int b = a < 0 ? 0 : (a > 952 ? 952 : a);
    return b & ~7;
}

// scores are pre-scaled by log2(e) (folded into q and pos_q scales), so
// softmax uses exp2 throughout — mathematically exact.

// ---------------- prep: all fp32->bf16 converts + mask flags, ONE dispatch ----------------
__global__ __launch_bounds__(256) void prep_k(
    const float* __restrict__ hid_f, const float* __restrict__ win_f,
    const float* __restrict__ rel_f, const float* __restrict__ wpos_f,
    const float* __restrict__ wposq_f, const int* __restrict__ amask,
    short* __restrict__ hid_bf, short* __restrict__ win_bf,
    short* __restrict__ rel_bf, short* __restrict__ wpos_bf,
    short* __restrict__ wposq_bf, int* __restrict__ flags)
{
    __shared__ int sall[4], sany[4];
    const int b = blockIdx.x, tid = threadIdx.x;
    if (b < 4096) {
        const float* in; short* out; int idx;
        if (b < 1024)      { in = hid_f;  out = hid_bf;  idx = b * 256 + tid; }
        else if (b < 2560) { in = win_f;  out = win_bf;  idx = (b - 1024) * 256 + tid; }
        else {
            int t = b - 2560, sel = t >> 9;
            in  = sel == 0 ? rel_f  : (sel == 1 ? wpos_f  : wposq_f);
            out = sel == 0 ? rel_bf : (sel == 1 ? wpos_bf : wposq_bf);
            idx = (t & 511) * 256 + tid;
        }
        const float4 a = ((const float4*)in)[idx * 2];
        const float4 b4 = ((const float4*)in)[idx * 2 + 1];
        bf16x8 r;
        r[0] = f2bf(a.x); r[1] = f2bf(a.y); r[2] = f2bf(a.z); r[3] = f2bf(a.w);
        r[4] = f2bf(b4.x); r[5] = f2bf(b4.y); r[6] = f2bf(b4.z); r[7] = f2bf(b4.w);
        ((bf16x8*)out)[idx] = r;
    } else {
        const int mb = b - 4096;
        const int jt = mb & 31, it = mb >> 5;
        const int r = tid >> 2, cseg = (tid & 3) << 4;
        const int4* rp = (const int4*)(amask + (size_t)(it * 64 + r) * SEQ + jt * 64 + cseg);
        int allnz = 1, anynz = 0;
        #pragma unroll
        for (int e = 0; e < 4; ++e) {
            int4 v = rp[e];
            allnz &= (v.x != 0) & (v.y != 0) & (v.z != 0) & (v.w != 0);
            anynz |= (v.x != 0) | (v.y != 0) | (v.z != 0) | (v.w != 0);
        }
        unsigned long long ba = __ballot(allnz != 0);
        unsigned long long bo = __ballot(anynz != 0);
        const int w = tid >> 6;
        if ((tid & 63) == 0) { sall[w] = (ba == ~0ull); sany[w] = (bo != 0ull); }
        __syncthreads();
        if (tid == 0) {
            int all4 = sall[0] & sall[1] & sall[2] & sall[3];
            int any4 = sany[0] | sany[1] | sany[2] | sany[3];
            flags[it * 32 + jt] = all4 ? 2 : (any4 ? 1 : 0);
        }
    }
}

// ---------------- shared MFMA GEMM core: C[128x64] += A[128xK] * B[64xK]^T ----------------
static __device__ __forceinline__ void gemm_tile(
    const short* __restrict__ Ag, int lda,
    const short* __restrict__ Bg, int ldb,
    int K, short* As, short* Bs, f32x4 (&acc)[4][2])
{
    const int tid = threadIdx.x;
    const int lane = tid & 63, w = tid >> 6;
    const int g = lane >> 4, ln = lane & 15;
    const int wm = (w >> 1) * 64, wn = (w & 1) * 32;
    for (int kt = 0; kt < K; kt += 64) {
        __syncthreads();
        #pragma unroll
        for (int it = 0; it < 4; ++it) {
            int c = it * 256 + tid;
            int r = c >> 3, cb = c & 7;
            uint4 v = *(const uint4*)(Ag + (size_t)r * lda + kt + ((cb ^ (r & 7)) << 3));
            *(uint4*)(As + r * 64 + cb * 8) = v;
        }
        #pragma unroll
        for (int it = 0; it < 2; ++it) {
            int c = it * 256 + tid;
            int r = c >> 3, cb = c & 7;
            uint4 v = *(const uint4*)(Bg + (size_t)r * ldb + kt + ((cb ^ (r & 7)) << 3));
            *(uint4*)(Bs + r * 64 + cb * 8) = v;
        }
        __syncthreads();
        #pragma unroll
        for (int k0 = 0; k0 < 2; ++k0) {
            bf16x8 bfr[2];
            #pragma unroll
            for (int nf = 0; nf < 2; ++nf) {
                int rr = wn + nf * 16 + ln;
                int kc = (k0 * 4 + g) ^ (rr & 7);
                bfr[nf] = *(const bf16x8*)(Bs + rr * 64 + kc * 8);
            }
            #pragma unroll
            for (int mf = 0; mf < 4; ++mf) {
                int rr = wm + mf * 16 + ln;
                int kc = (k0 * 4 + g) ^ (rr & 7);
                bf16x8 afr = *(const bf16x8*)(As + rr * 64 + kc * 8);
                #pragma unroll
                for (int nf = 0; nf < 2; ++nf)
                    acc[mf][nf] = __builtin_amdgcn_mfma_f32_16x16x32_bf16(afr, bfr[nf], acc[mf][nf], 0, 0, 0);
            }
        }
    }
}

// ---------------- QKV projection + pos_k/pos_q in ONE dispatch (1024 blocks = 4/CU) ----------------
__global__ __launch_bounds__(256) void qkvpos_k(
    const short* __restrict__ hid, const short* __restrict__ win,
    const float* __restrict__ q_bias, const float* __restrict__ v_bias,
    const short* __restrict__ rel, const short* __restrict__ wpos, const short* __restrict__ wposq,
    const float* __restrict__ b_posq,
    short* __restrict__ qT, short* __restrict__ kT, short* __restrict__ vTt,
    short* __restrict__ posk, short* __restrict__ posq)
{
    __shared__ __align__(16) short As[128 * 64];
    __shared__ __align__(16) short Bs[64 * 64];
    const int tid = threadIdx.x, lane = tid & 63, w = tid >> 6;
    const int g = lane >> 4, ln = lane & 15;
    const int wm = (w >> 1) * 64, wn = (w & 1) * 32;
    const int x = blockIdx.x;
    // q / pos_q scales include log2(e) for exp2-softmax
    const float inv_s = 0.07216878364870323f * 1.4426950408889634f;
    f32x4 acc[4][2] = {};

    if (x < 768) {
        // ---- qkv ----
        const int bx = x % 48, by = x / 48;
        const int m0 = by * 128, n0 = bx * 64;
        gemm_tile(hid + (size_t)m0 * HID, HID, win + (size_t)n0 * HID, HID, HID, As, Bs, acc);
        #pragma unroll
        for (int nf = 0; nf < 2; ++nf) {
            const int n = n0 + wn + nf * 16 + ln;
            const int h = n / 192, c = n % 192;
            #pragma unroll
            for (int mf = 0; mf < 4; ++mf) {
                const int mb = m0 + wm + mf * 16 + 4 * g;
                if (c < 64) {
                    float qb = q_bias[h * 64 + c];
                    #pragma unroll
                    for (int reg = 0; reg < 4; ++reg)
                        qT[((size_t)h * SEQ + mb + reg) * DH + c] = f2bf((acc[mf][nf][reg] + qb) * inv_s);
                } else if (c < 128) {
                    #pragma unroll
                    for (int reg = 0; reg < 4; ++reg)
                        kT[((size_t)h * SEQ + mb + reg) * DH + (c - 64)] = f2bf(acc[mf][nf][reg]);
                } else {
                    float vb = v_bias[h * 64 + (c - 128)];
                    uint2 u;
                    u.x = cvtpk(acc[mf][nf][0] + vb, acc[mf][nf][1] + vb);
                    u.y = cvtpk(acc[mf][nf][2] + vb, acc[mf][nf][3] + vb);
                    *(uint2*)(vTt + ((size_t)h * DH + (c - 128)) * SEQ + mb) = u;
                }
            }
        }
    } else {
        // ---- pos ----
        const int t = x - 768;
        const int which = t >> 7, rest = t & 127;
        const int m0 = (rest / 16) * 128, n0 = (rest % 16) * 64;
        const short* Bg = (which ? wposq : wpos) + (size_t)n0 * HID;
        gemm_tile(rel + (size_t)m0 * HID, HID, Bg, HID, HID, As, Bs, acc);
        #pragma unroll
        for (int mf = 0; mf < 4; ++mf) {
            #pragma unroll
            for (int nf = 0; nf < 2; ++nf) {
                #pragma unroll
                for (int reg = 0; reg < 4; ++reg) {
                    int s = m0 + wm + mf * 16 + 4 * g + reg;
                    int o = n0 + wn + nf * 16 + ln;
                    int h = o >> 6, c = o & 63;
                    float v = acc[mf][nf][reg];
                    if (which) posq[((size_t)h * S2 + s) * DH + c] = f2bf((v + b_posq[o]) * inv_s);
                    else       posk[((size_t)h * S2 + s) * DH + c] = f2bf(v);
                }
            }
        }
    }
}

// ---------------- band GEMMs (c2p / p2c): 4 n-tiles per staged X tile ----------------
__global__ __launch_bounds__(256) void band_mfma_k(
    const short* __restrict__ qT, const short* __restrict__ kT,
    const short* __restrict__ posk, const short* __restrict__ posq,
    short* __restrict__ c2p, short* __restrict__ p2c)
{
    __shared__ __align__(16) short Xs[128 * 64];
    __shared__ __align__(16) short Ps[64 * 64];
    const int tid = threadIdx.x, lane = tid & 63, w = tid >> 6;
    const int g = lane >> 4, ln = lane & 15;
    const int m0 = blockIdx.y * 128, n0base = blockIdx.x * 256;
    const int head = blockIdx.z >> 1, which = blockIdx.z & 1;
    const short* Xg = (which ? kT : qT) + (size_t)head * SEQ * DH + (size_t)m0 * DH;
    const short* Pg0 = (which ? posq : posk) + (size_t)head * S2 * DH;
    short* outb = (which ? p2c : c2p) + (size_t)head * SEQ * S2;
    // stage X tile once (reused for 4 n-tiles)
    #pragma unroll
    for (int it = 0; it < 4; ++it) {
        int c = it * 256 + tid;
        int r = c >> 3, cb = c & 7;
        *(uint4*)(Xs + r * 64 + cb * 8) = *(const uint4*)(Xg + (size_t)r * DH + ((cb ^ (r & 7)) << 3));
    }
    const int wm = w * 32;
    for (int sub = 0; sub < 4; ++sub) {
        const int n0 = n0base + sub * 64;
        const short* Pg = Pg0 + (size_t)n0 * DH;
        __syncthreads();   // (1st iter: Xs ready; later: previous Ps reads done)
        #pragma unroll
        for (int it = 0; it < 2; ++it) {
            int c = it * 256 + tid;
            int r = c >> 3, cb = c & 7;
            *(uint4*)(Ps + r * 64 + cb * 8) = *(const uint4*)(Pg + (size_t)r * DH + ((cb ^ (r & 7)) << 3));
        }
        __syncthreads();
        f32x4 acc[2][4] = {};
        #pragma unroll
        for (int k0 = 0; k0 < 2; ++k0) {
            bf16x8 af[4];
            #pragma unroll
            for (int nf = 0; nf < 4; ++nf) {
                int rr = nf * 16 + ln;
                af[nf] = *(const bf16x8*)(Ps + rr * 64 + (((k0 * 4 + g) ^ (rr & 7)) << 3));
            }
            #pragma unroll
            for (int mf = 0; mf < 2; ++mf) {
                int rr = wm + mf * 16 + ln;
                bf16x8 xf = *(const bf16x8*)(Xs + rr * 64 + (((k0 * 4 + g) ^ (rr & 7)) << 3));
                #pragma unroll
                for (int nf = 0; nf < 4; ++nf)
                    acc[mf][nf] = __builtin_amdgcn_mfma_f32_16x16x32_bf16(af[nf], xf, acc[mf][nf], 0, 0, 0);
            }
        }
        // D[4g+reg] -> pos row (n-local), D[ln] -> X row (m-local)
        #pragma unroll
        for (int mf = 0; mf < 2; ++mf) {
            const int m = m0 + wm + mf * 16 + ln;
            #pragma unroll
            for (int nf = 0; nf < 4; ++nf) {
                uint2 u;
                u.x = cvtpk(acc[mf][nf][0], acc[mf][nf][1]);
                u.y = cvtpk(acc[mf][nf][2], acc[mf][nf][3]);
                *(uint2*)(outb + (size_t)m * S2 + n0 + nf * 16 + 4 * g) = u;
            }
        }
    }
}

// ---------------- MFMA flash attention: 3-way bias path + setprio + raw v_exp ----------------
__global__ __launch_bounds__(256) void attn_mfma_k(
    const short* __restrict__ qT, const short* __restrict__ kT, const short* __restrict__ vTt,
    const short* __restrict__ c2p, const short* __restrict__ p2c,
    const int* __restrict__ amask, const int* __restrict__ flags,
    float* __restrict__ out)
{
    // two full staging buffers, 17408 shorts each:
    //   Ks [0,4096)  Vs [4096,8192)  Phw [8192,12800)  Chw [12800,17408)
    __shared__ __align__(16) char pool[69632];
    short* const lds = (short*)pool;
    const int tid = threadIdx.x, lane = tid & 63, w = tid >> 6;
    const int g = lane >> 4, ln = lane & 15;
    const int h = blockIdx.y, it = blockIdx.x;
    const int i0 = it * 64;
    const int iw = i0 + w * 16;
    const short* qh = qT + (size_t)h * SEQ * DH;
    const short* kh = kT + (size_t)h * SEQ * DH;
    const short* vh = vTt + (size_t)h * DH * SEQ;
    const short* ch = c2p + (size_t)h * SEQ * S2;
    const short* ph = p2c + (size_t)h * SEQ * S2;

    bf16x8 aq[2];
    aq[0] = *(const bf16x8*)(qh + (size_t)(iw + ln) * DH + 0  + g * 8);
    aq[1] = *(const bf16x8*)(qh + (size_t)(iw + ln) * DH + 32 + g * 8);

    f32x4 o4[4] = {};
    float mrow = -1.0e30f, lrow = 0.f;   // lane-local row stats (row i = iw + ln)

    const int fbase = it * 32;
    const int r0 = tid >> 3,          cb0 = tid & 7;
    const int r1 = (256 + tid) >> 3,  cb1 = tid & 7;
    const int ksw0 = (cb0 ^ (r0 & 7)) << 3, ksw1 = (cb1 ^ (r1 & 7)) << 3;
    const int wr = tid >> 2, wu = (tid & 3) * 16;

    uint4 kr0, kr1, vr0, vr1, cw0, cw1, pw0, pw1, cw2, pw2;

    auto issue = [&](int jt) {
        const int j0 = jt * 64;
        kr0 = *(const uint4*)(kh + (size_t)(j0 + r0) * DH + ksw0);
        vr0 = *(const uint4*)(vh + (size_t)r0 * SEQ + j0 + ksw0);
        kr1 = *(const uint4*)(kh + (size_t)(j0 + r1) * DH + ksw1);
        vr1 = *(const uint4*)(vh + (size_t)r1 * SEQ + j0 + ksw1);
        int bc = wbase(i0 + wr - j0 + 449);
        cw0 = *(const uint4*)(ch + (size_t)(i0 + wr) * S2 + bc + wu);
        cw1 = *(const uint4*)(ch + (size_t)(i0 + wr) * S2 + bc + wu + 8);
        int bp = wbase(i0 - j0 - wr + 512);
        pw0 = *(const uint4*)(ph + (size_t)(j0 + wr) * S2 + bp + wu);
        pw1 = *(const uint4*)(ph + (size_t)(j0 + wr) * S2 + bp + wu + 8);
        if (tid < 64) {
            int bc2 = wbase(i0 + tid - j0 + 449);
            cw2 = *(const uint4*)(ch + (size_t)(i0 + tid) * S2 + bc2 + 64);
            int bp2 = wbase(i0 - j0 - tid + 512);
            pw2 = *(const uint4*)(ph + (size_t)(j0 + tid) * S2 + bp2 + 64);
        }
    };
    auto commit = [&](int bo) {
        short* Ks  = lds + bo;
        short* Vs  = lds + bo + 4096;
        short* Phw = lds + bo + 8192;
        short* Chw = lds + bo + 12800;
        *(uint4*)(Ks + r0 * 64 + cb0 * 8) = kr0;
        *(uint4*)(Vs + r0 * 64 + cb0 * 8) = vr0;
        *(uint4*)(Ks + r1 * 64 + cb1 * 8) = kr1;
        *(uint4*)(Vs + r1 * 64 + cb1 * 8) = vr1;
        *(uint4*)(Chw + wr * 72 + wu) = cw0;
        *(uint4*)(Chw + wr * 72 + wu + 8) = cw1;
        *(uint4*)(Phw + wr * 72 + wu) = pw0;
        *(uint4*)(Phw + wr * 72 + wu + 8) = pw1;
        if (tid < 64) {
            *(uint4*)(Chw + tid * 72 + 64) = cw2;
            *(uint4*)(Phw + tid * 72 + 64) = pw2;
        }
    };

    // prologue: stage tile 0 into buffer 0
    issue(0);
    int flag_cur = flags[fbase];
    commit(0);
    __syncthreads();

    const int il = w * 16 + ln;     // i-local (this lane's row)
    const int i  = i0 + il;

    int bo = 0;
    for (int t = 0; t < 32; ++t) {
        const int j0 = t * 64;
        int flag_next = 0;
        if (t < 31) { flag_next = flags[fbase + t + 1]; issue(t + 1); }

        short* Ks  = lds + bo;
        short* Vs  = lds + bo + 4096;
        short* Phw = lds + bo + 8192;
        short* Chw = lds + bo + 12800;
        short* Psw = Chw + w * 1152;   // wave-private alias of Chw rows [16w,16w+16)

        if (flag_cur != 0) {
            // S^T = K Q^T: D col=ln -> i-local, row=4g+reg -> j-local
            f32x4 sfr[4];
            #pragma unroll
            for (int nf = 0; nf < 4; ++nf) sfr[nf] = (f32x4){0.f, 0.f, 0.f, 0.f};
            __builtin_amdgcn_s_setprio(1);
            #pragma unroll
            for (int k0 = 0; k0 < 2; ++k0) {
                #pragma unroll
                for (int nf = 0; nf < 4; ++nf) {
                    int rr = nf * 16 + ln;
                    bf16x8 ak = *(const bf16x8*)(Ks + rr * 64 + (((k0 * 4 + g) ^ (rr & 7)) << 3));
                    sfr[nf] = __builtin_amdgcn_mfma_f32_16x16x32_bf16(ak, aq[k0], sfr[nf], 0, 0, 0);
                }
            }
            __builtin_amdgcn_s_setprio(0);

            const int d = i0 - j0;
            float p[4][4];
            if (d >= -448 && d <= 384 && flag_cur == 2) {
                // FAST PATH: no clamps can engage; indices collapse to
                // per-tile bases + compile-time immediates.
                const int a = i - j0 + 449;                       // lane const
                const short* Cb = Chw + il * 72 + (a & 7) - 4 * g;
                const int cg = d + 512 - 4 * g;
                const int pbase = il + 288 * g;
                const int pb0 = pbase + (cg & 7);
                const int pb1 = pbase + ((cg - 1) & 7);
                const int pb2 = pbase + ((cg - 2) & 7);
                const int pb3 = pbase + ((cg - 3) & 7);
                #pragma unroll
                for (int nf = 0; nf < 4; ++nf) {
                    p[nf][0] = sfr[nf][0] + bf2f(Cb[63 - 16 * nf - 0]) + bf2f(Phw[pb0 + 1152 * nf + 0]);
                    p[nf][1] = sfr[nf][1] + bf2f(Cb[63 - 16 * nf - 1]) + bf2f(Phw[pb1 + 1152 * nf + 72]);
                    p[nf][2] = sfr[nf][2] + bf2f(Cb[63 - 16 * nf - 2]) + bf2f(Phw[pb2 + 1152 * nf + 144]);
                    p[nf][3] = sfr[nf][3] + bf2f(Cb[63 - 16 * nf - 3]) + bf2f(Phw[pb3 + 1152 * nf + 216]);
                }
            } else if (flag_cur == 2 && (d <= -576 || d >= 576)) {
                // SATURATED PATH: every s clamps to the same end (0 or 1023).
                // Staged window index is provably 0 (low end) or 71 (high end).
                const int q = d < 0 ? 0 : 71;
                const float cb = bf2f(Chw[il * 72 + q]);   // lane-const c2p[i][s̄]
                #pragma unroll
                for (int nf = 0; nf < 4; ++nf) {
                    const int pb = (16 * nf + 4 * g) * 72 + q;
                    p[nf][0] = sfr[nf][0] + cb + bf2f(Phw[pb]);
                    p[nf][1] = sfr[nf][1] + cb + bf2f(Phw[pb + 72]);
                    p[nf][2] = sfr[nf][2] + cb + bf2f(Phw[pb + 144]);
                    p[nf][3] = sfr[nf][3] + cb + bf2f(Phw[pb + 216]);
                }
            } else {
                // GENERAL PATH: clamped windows + optional mask
                const short* Crow = Chw + il * 72 - wbase(i - j0 + 449);
                const int Cc = i0 - j0 + 512;
                #pragma unroll
                for (int nf = 0; nf < 4; ++nf) {
                    #pragma unroll
                    for (int reg = 0; reg < 4; ++reg) {
                        int jr = 16 * nf + 4 * g + reg;
                        int s = i - (j0 + jr) + 512; s = s < 0 ? 0 : (s > 1023 ? 1023 : s);
                        int wbp = Cc - jr; wbp = wbp < 0 ? 0 : (wbp > 952 ? 952 : wbp); wbp &= ~7;
                        float sc = sfr[nf][reg] + bf2f(Crow[s]) + bf2f(Phw[jr * 72 + (s - wbp)]);
                        if (flag_cur != 2)
                            sc = amask[(size_t)i * SEQ + (j0 + jr)] ? sc : -1.0e30f;
                        p[nf][reg] = sc;
                    }
                }
            }

            // online softmax (exp2 domain): row i lane-local + 2 cross-g shuffles
            float mx = p[0][0];
            #pragma unroll
            for (int nf = 0; nf < 4; ++nf)
                #pragma unroll
                for (int reg = 0; reg < 4; ++reg) mx = fmaxf(mx, p[nf][reg]);
            mx = fmaxf(mx, __shfl_xor(mx, 16, 64));
            mx = fmaxf(mx, __shfl_xor(mx, 32, 64));
            float nm = fmaxf(mrow, mx);
            float sc, rs = 0.f;
            if (flag_cur == 2) {
                sc = fexp2(mrow - nm);
                #pragma unroll
                for (int nf = 0; nf < 4; ++nf)
                    #pragma unroll
                    for (int reg = 0; reg < 4; ++reg) {
                        float e = fexp2(p[nf][reg] - nm);
                        p[nf][reg] = e; rs += e;
                    }
            } else {
                bool live = nm > -5.0e29f;
                sc = live ? fexp2(mrow - nm) : 1.f;
                #pragma unroll
                for (int nf = 0; nf < 4; ++nf)
                    #pragma unroll
                    for (int reg = 0; reg < 4; ++reg) {
                        float e = live ? fexp2(p[nf][reg] - nm) : 0.f;
                        p[nf][reg] = e; rs += e;
                    }
            }
            rs += __shfl_xor(rs, 16, 64);
            rs += __shfl_xor(rs, 32, 64);
            lrow = lrow * sc + rs;
            mrow = nm;

            // write P into wave-private aliased region: cvt_pk + 4 aligned b64 stores
            #pragma unroll
            for (int nf = 0; nf < 4; ++nf) {
                uint2 u;
                u.x = cvtpk(p[nf][0], p[nf][1]);
                u.y = cvtpk(p[nf][2], p[nf][3]);
                *(uint2*)(Psw + ln * 72 + 16 * nf + 4 * g) = u;
            }

            // rescale O^T: lane owns col i = ln -> lane-local scale
            #pragma unroll
            for (int mf = 0; mf < 4; ++mf)
                #pragma unroll
                for (int reg = 0; reg < 4; ++reg) o4[mf][reg] *= sc;

            // O^T += V^T * P^T
            __builtin_amdgcn_s_setprio(1);
            #pragma unroll
            for (int k0 = 0; k0 < 2; ++k0) {
                bf16x8 bp = *(const bf16x8*)(Psw + ln * 72 + k0 * 32 + g * 8);
                #pragma unroll
                for (int mf = 0; mf < 4; ++mf) {
                    int rr = mf * 16 + ln;
                    bf16x8 av = *(const bf16x8*)(Vs + rr * 64 + (((k0 * 4 + g) ^ (rr & 7)) << 3));
                    o4[mf] = __builtin_amdgcn_mfma_f32_16x16x32_bf16(av, bp, o4[mf], 0, 0, 0);
                }
            }
            __builtin_amdgcn_s_setprio(0);
        }

        if (t < 31) commit(bo ^ 17408);   // writes go to the OTHER buffer
        __syncthreads();                  // single barrier per tile
        bo ^= 17408;
        flag_cur = flag_next;
    }

    // ---- normalize (lane-local l) and store via LDS transpose, coalesced ----
    float rinv = (mrow > -5.0e29f && lrow > 0.f) ? 1.f / lrow : 0.f;
    __syncthreads();
    float* Tf = (float*)pool;   // 64 x 68 f32 = 17408 B (fits pool)
    #pragma unroll
    for (int mf = 0; mf < 4; ++mf)
        #pragma unroll
        for (int reg = 0; reg < 4; ++reg)
            Tf[(w * 16 + ln) * 68 + mf * 16 + 4 * g + reg] = o4[mf][reg] * rinv;
    __syncthreads();
    {
        const int r = tid >> 2, sgm = (tid & 3) << 4;
        float* dst = out + (size_t)(i0 + r) * HID + h * 64 + sgm;
        #pragma unroll
        for (int k = 0; k < 4; ++k)
            ((float4*)dst)[k] = *(float4*)(Tf + r * 68 + sgm + k * 4);
    }
}

extern "C" void kernel_launch(void* const* d_in, const int* in_sizes, int n_in,
                              void* d_out, int out_size, void* d_ws, size_t ws_size,
                              hipStream_t stream)
{
    const float* hidden  = (const float*)d_in[0];
    const int*   amask   = (const int*)  d_in[1];
    const float* W_in    = (const float*)d_in[2];
    const float* q_bias  = (const float*)d_in[3];
    const float* v_bias  = (const float*)d_in[4];
    const float* W_pos   = (const float*)d_in[5];
    const float* W_posq  = (const float*)d_in[6];
    const float* b_posq  = (const float*)d_in[7];
    const float* rel_emb = (const float*)d_in[8];
    float* out = (float*)d_out;

    short* ws = (short*)d_ws;
    // persistent (live into attn):
    short* qT   = ws;                    // 2,097,152
    short* kT   = ws + 2097152;          // 2,097,152
    short* vTt  = ws + 4194304;          // 2,097,152
    short* c2p  = ws + 6291456;          // 33,554,432
    short* p2c  = ws + 39845888;         // 33,554,432
    // scratch region:
    short* scr      = ws + 73400320;
    short* hid_bf   = scr;               // 2,097,152
    short* win_bf   = scr + 2097152;     // 3,145,728
    short* rel_bf   = scr + 5242880;     // 1,048,576
    short* wpos_bf  = scr + 6291456;     // 1,048,576
    short* wposq_bf = scr + 7340032;     // 1,048,576
    short* posk     = scr + 8388608;     // 1,048,576
    short* posq     = scr + 9437184;     // 1,048,576
    int*   flags    = (int*)(scr + 10485760); // 1,024 ints

    prep_k<<<5120, 256, 0, stream>>>(hidden, W_in, rel_emb, W_pos, W_posq, amask,
                                     hid_bf, win_bf, rel_bf, wpos_bf, wposq_bf, flags);
    qkvpos_k<<<1024, 256, 0, stream>>>(hid_bf, win_bf, q_bias, v_bias,
                                       rel_bf, wpos_bf, wposq_bf, b_posq,
                                       qT, kT, vTt, posk, posq);
    band_mfma_k<<<dim3(4, 16, 32), 256, 0, stream>>>(qT, kT, posk, posq, c2p, p2c);
    attn_mfma_k<<<dim3(32, 16), 256, 0, stream>>>(qT, kT, vTt, c2p, p2c, amask, flags, out);
}